// Round 4
// baseline (559.992 us; speedup 1.0000x reference)
//
#include <hip/hip_runtime.h>
#include <cstdint>
#include <cstddef>

typedef __attribute__((ext_vector_type(8))) short short8;
typedef __attribute__((ext_vector_type(4))) float f32x4;
typedef __attribute__((ext_vector_type(4))) _Float16 half4v;

// ---------------- bf16 split helpers (round-to-nearest-even) ----------------

__device__ inline unsigned short f2bf(float f) {
    unsigned int u = __float_as_uint(f);
    u = u + 0x7fff + ((u >> 16) & 1);
    return (unsigned short)(u >> 16);
}
__device__ inline float bf2f(unsigned short h) {
    return __uint_as_float(((unsigned int)h) << 16);
}
__device__ inline void split2(float v, unsigned short& hi, unsigned short& lo) {
    hi = f2bf(v);
    lo = f2bf(v - bf2f(hi));
}

// ---------------- preprocessing kernels ----------------

__global__ void zero_ints(int* p, int n) {
    int i = blockIdx.x * 256 + threadIdx.x;
    if (i < n) p[i] = 0;
}

__global__ void count_deg(const int* __restrict__ dst, int* __restrict__ cnt, int E) {
    int i = blockIdx.x * 256 + threadIdx.x;
    if (i < E) atomicAdd(&cnt[dst[i]], 1);
}

__global__ void compute_dis(const int* __restrict__ cnt, float* __restrict__ dis, int N) {
    int i = blockIdx.x * 256 + threadIdx.x;
    if (i < N) dis[i] = rsqrtf((float)cnt[i] + 1.0f);
}

// ---------------- 3-phase parallel exclusive scan over cnt -> rp, cursor ----------------

__global__ __launch_bounds__(256) void scan_block_sums(const int* __restrict__ cnt,
                                                       int* __restrict__ partials, int N) {
    __shared__ int s[256];
    int t = threadIdx.x;
    int base = blockIdx.x * 1024 + t * 4;
    int v = 0;
    if (base + 3 < N) {
        int4 d = *(const int4*)&cnt[base];
        v = d.x + d.y + d.z + d.w;
    } else {
        for (int j = 0; j < 4; ++j) if (base + j < N) v += cnt[base + j];
    }
    s[t] = v;
    __syncthreads();
    for (int off = 128; off > 0; off >>= 1) {
        if (t < off) s[t] += s[t + off];
        __syncthreads();
    }
    if (t == 0) partials[blockIdx.x] = s[0];
}

__global__ __launch_bounds__(256) void scan_partials(int* __restrict__ partials, int nb,
                                                     int* __restrict__ rp, int N) {
    __shared__ int s[256];
    int t = threadIdx.x;
    int base = t * 4;
    int v0 = 0, v1 = 0, v2 = 0, v3 = 0;
    if (base < nb)     v0 = partials[base];
    if (base + 1 < nb) v1 = partials[base + 1];
    if (base + 2 < nb) v2 = partials[base + 2];
    if (base + 3 < nb) v3 = partials[base + 3];
    s[t] = v0 + v1 + v2 + v3;
    __syncthreads();
    for (int off = 1; off < 256; off <<= 1) {
        int v = s[t];
        int u = (t >= off) ? s[t - off] : 0;
        __syncthreads();
        s[t] = v + u;
        __syncthreads();
    }
    int run = (t == 0) ? 0 : s[t - 1];
    if (base < nb)     { partials[base] = run;     run += v0; }
    if (base + 1 < nb) { partials[base + 1] = run; run += v1; }
    if (base + 2 < nb) { partials[base + 2] = run; run += v2; }
    if (base + 3 < nb) { partials[base + 3] = run; run += v3; }
    if (t == 255) rp[N] = s[255];
}

__global__ __launch_bounds__(256) void scan_write(const int* __restrict__ cnt,
                                                  const int* __restrict__ partials,
                                                  int* __restrict__ rp,
                                                  int* __restrict__ cursor, int N) {
    __shared__ int s[256];
    int t = threadIdx.x;
    int base = blockIdx.x * 1024 + t * 4;
    int v0 = 0, v1 = 0, v2 = 0, v3 = 0;
    if (base + 3 < N) {
        int4 d = *(const int4*)&cnt[base];
        v0 = d.x; v1 = d.y; v2 = d.z; v3 = d.w;
    } else {
        if (base < N)     v0 = cnt[base];
        if (base + 1 < N) v1 = cnt[base + 1];
        if (base + 2 < N) v2 = cnt[base + 2];
    }
    s[t] = v0 + v1 + v2 + v3;
    __syncthreads();
    for (int off = 1; off < 256; off <<= 1) {
        int v = s[t];
        int u = (t >= off) ? s[t - off] : 0;
        __syncthreads();
        s[t] = v + u;
        __syncthreads();
    }
    int run = partials[blockIdx.x] + ((t == 0) ? 0 : s[t - 1]);
    int4 o;
    o.x = run; run += v0;
    o.y = run; run += v1;
    o.z = run; run += v2;
    o.w = run; run += v3;
    if (base + 3 < N) {
        *(int4*)&rp[base] = o;
        *(int4*)&cursor[base] = o;
    } else {
        if (base < N)     { rp[base] = o.x;     cursor[base] = o.x; }
        if (base + 1 < N) { rp[base + 1] = o.y; cursor[base + 1] = o.y; }
        if (base + 2 < N) { rp[base + 2] = o.z; cursor[base + 2] = o.z; }
    }
}

// edata[pos] = (src, bitcast(norm)) — one 8B record per edge
__global__ void scatter_edges(const int* __restrict__ src, const int* __restrict__ dstv,
                              const float* __restrict__ dis, int* __restrict__ cursor,
                              int2* __restrict__ edata, int E) {
    int i = blockIdx.x * 256 + threadIdx.x;
    if (i < E) {
        int s = src[i], d = dstv[i];
        int pos = atomicAdd(&cursor[d], 1);
        edata[pos] = make_int2(s, __float_as_int(dis[s] * dis[d]));
    }
}

__global__ void build_h0(const float* __restrict__ x, const float* __restrict__ xm,
                         float* __restrict__ h0, int N) {
    int i = blockIdx.x * 256 + threadIdx.x;
    if (i < N * 16) {
        int node = i >> 4, f = i & 15;
        h0[i] = (f < 8) ? x[node * 10 + f] : xm[node * 10 + f - 8];
    }
}

// ---------------- W split into MFMA B-fragment order ----------------

__global__ __launch_bounds__(256) void wsplit_kernel(const float* __restrict__ Wh,
                                                     const float* __restrict__ Wr1,
                                                     unsigned short* __restrict__ whi,
                                                     unsigned short* __restrict__ wlo) {
    int g = blockIdx.x * 256 + threadIdx.x;   // 5*16384 entries
    int l = g >> 14;
    int idx = g & 16383;
    int j = idx & 7;
    int lane = (idx >> 3) & 63;
    int tcchunk = idx >> 9;                   // 0..31
    int tc = tcchunk & 7, chunk = tcchunk >> 3;
    int k = chunk * 32 + (lane >> 4) * 8 + j;
    int n = tc * 16 + (lane & 15);
    float v = (l < 4) ? Wh[l * 16384 + k * 128 + n] : Wr1[k * 128 + n];
    unsigned short hi, lo;
    split2(v, hi, lo);
    whi[g] = hi;
    wlo[g] = lo;
}

// ---------------- aggregation, 16-wide (layer 0): fp32 out ----------------
// edata preloaded by 16 lanes (covers deg<=16, P(deg>16)~0.4%), batch-8 gathers.
// FP add order identical to the direct version (self, then edges ascending).

__global__ __launch_bounds__(256) void agg16_kernel(const float* __restrict__ h,
                                                    const int* __restrict__ rp,
                                                    const int2* __restrict__ edata,
                                                    const float* __restrict__ dis,
                                                    float* __restrict__ out, int N) {
    int node = blockIdx.x * 16 + (threadIdx.x >> 4);
    int tl = threadIdx.x & 15;
    if (node >= N) return;
    int beg = rp[node], end = rp[node + 1];
    int deg = end - beg;
    float di = dis[node];
    float acc = h[(size_t)node * 16 + tl] * (di * di);
    int2 my = make_int2(0, 0);
    if (deg > 0) my = edata[beg + min(tl, deg - 1)];
    int pre = min(deg, 16);
    int i = 0;
    while (i < pre) {
        int c = min(8, pre - i);
        float v[8];
        #pragma unroll
        for (int j = 0; j < 8; ++j) {
            if (j < c) {
                int sx = __shfl(my.x, i + j, 16);
                v[j] = h[(size_t)sx * 16 + tl];
            }
        }
        #pragma unroll
        for (int j = 0; j < 8; ++j) {
            if (j < c) {
                float nr = __int_as_float(__shfl(my.y, i + j, 16));
                acc += v[j] * nr;
            }
        }
        i += c;
    }
    for (int e = beg + 16; e < end; ++e) {
        int2 ee = edata[e];
        acc += h[(size_t)ee.x * 16 + tl] * __int_as_float(ee.y);
    }
    out[(size_t)node * 16 + tl] = acc;
}

// ---------------- layer-0 GEMM (K=16): VALU fp32, W in LDS; fp16 out + relu ----------------

template <int K, int OMODE>
__global__ __launch_bounds__(256, 4) void gemm_kernel(const float* __restrict__ A,
                                                      const float* __restrict__ W,
                                                      const float* __restrict__ bias,
                                                      void* __restrict__ outv, int N) {
    constexpr int KS = (K < 64) ? K : 64;
    __shared__ float sW[KS * 128];
    int t = threadIdx.x;
    int row0 = blockIdx.x * 64;
    int cg = t & 31, rg = t >> 5;
    int c0 = cg * 4;
    int r0 = row0 + rg * 8;

    const float* Ar[8];
    #pragma unroll
    for (int i = 0; i < 8; ++i) {
        int rr = min(r0 + i, N - 1);
        Ar[i] = A + (size_t)rr * K;
    }

    float4 acc[8];
    #pragma unroll
    for (int i = 0; i < 8; ++i) acc[i] = make_float4(0.f, 0.f, 0.f, 0.f);

    for (int ks = 0; ks < K; ks += KS) {
        if (ks) __syncthreads();
        for (int i = t * 4; i < KS * 128; i += 1024) {
            *(float4*)&sW[i] = *(const float4*)&W[ks * 128 + i];
        }
        __syncthreads();

        for (int kk = 0; kk < KS; kk += 4) {
            float4 a[8];
            #pragma unroll
            for (int i = 0; i < 8; ++i) a[i] = *(const float4*)&Ar[i][ks + kk];
            float4 w[4];
            #pragma unroll
            for (int j = 0; j < 4; ++j) w[j] = *(const float4*)&sW[(kk + j) * 128 + c0];
            #pragma unroll
            for (int i = 0; i < 8; ++i) {
                const float* ap = (const float*)&a[i];
                #pragma unroll
                for (int j = 0; j < 4; ++j) {
                    float av = ap[j];
                    acc[i].x += av * w[j].x;
                    acc[i].y += av * w[j].y;
                    acc[i].z += av * w[j].z;
                    acc[i].w += av * w[j].w;
                }
            }
        }
    }

    float4 bb = *(const float4*)&bias[c0];
    #pragma unroll
    for (int i = 0; i < 8; ++i) {
        int row = r0 + i;
        if (row < N) {
            float4 v;
            v.x = fmaxf(acc[i].x + bb.x, 0.f); v.y = fmaxf(acc[i].y + bb.y, 0.f);
            v.z = fmaxf(acc[i].z + bb.z, 0.f); v.w = fmaxf(acc[i].w + bb.w, 0.f);
            if (OMODE == 1) {
                half4v o;
                o[0] = (_Float16)v.x; o[1] = (_Float16)v.y;
                o[2] = (_Float16)v.z; o[3] = (_Float16)v.w;
                *(half4v*)&((_Float16*)outv)[(size_t)row * 128 + c0] = o;
            } else {
                *(float4*)&((float*)outv)[(size_t)row * 128 + c0] = v;
            }
        }
    }
}

// ---------------- fused-layer gather helpers ----------------
// Pair-interleaved gathers: 4 loads for node A + 4 for node B in flight, then
// FMA A, FMA B. Per-node FP add order = edges ascending (bit-identical to the
// sequential version). c-conditions are uniform within each 32-lane group.

__device__ inline void gpair(const half4v* __restrict__ h4, int ln,
                             int2 myA, int preA, float4& A,
                             int2 myB, int preB, float4& B) {
    int i0 = 0, i1 = 0;
    while (i0 < preA || i1 < preB) {
        int cA = preA - i0; cA = cA > 4 ? 4 : cA;
        int cB = preB - i1; cB = cB > 4 ? 4 : cB;
        half4v vA[4], vB[4];
        #pragma unroll
        for (int j = 0; j < 4; ++j) {
            if (j < cA) {
                int sx = __shfl(myA.x, i0 + j, 32);
                vA[j] = h4[(size_t)sx * 32 + ln];
            }
        }
        #pragma unroll
        for (int j = 0; j < 4; ++j) {
            if (j < cB) {
                int sx = __shfl(myB.x, i1 + j, 32);
                vB[j] = h4[(size_t)sx * 32 + ln];
            }
        }
        #pragma unroll
        for (int j = 0; j < 4; ++j) {
            if (j < cA) {
                float nr = __int_as_float(__shfl(myA.y, i0 + j, 32));
                A.x += (float)vA[j][0] * nr; A.y += (float)vA[j][1] * nr;
                A.z += (float)vA[j][2] * nr; A.w += (float)vA[j][3] * nr;
            }
        }
        #pragma unroll
        for (int j = 0; j < 4; ++j) {
            if (j < cB) {
                float nr = __int_as_float(__shfl(myB.y, i1 + j, 32));
                B.x += (float)vB[j][0] * nr; B.y += (float)vB[j][1] * nr;
                B.z += (float)vB[j][2] * nr; B.w += (float)vB[j][3] * nr;
            }
        }
        i0 += cA; i1 += cB;
    }
}

__device__ inline void gtail(const half4v* __restrict__ h4, int ln,
                             const int2* __restrict__ edata, int e, int end, float4& A) {
    for (; e + 4 <= end; e += 4) {
        int2 e0 = edata[e], e1 = edata[e + 1], e2 = edata[e + 2], e3 = edata[e + 3];
        half4v v0 = h4[(size_t)e0.x * 32 + ln];
        half4v v1 = h4[(size_t)e1.x * 32 + ln];
        half4v v2 = h4[(size_t)e2.x * 32 + ln];
        half4v v3 = h4[(size_t)e3.x * 32 + ln];
        float n0 = __int_as_float(e0.y), n1 = __int_as_float(e1.y);
        float n2 = __int_as_float(e2.y), n3 = __int_as_float(e3.y);
        A.x += (float)v0[0] * n0; A.y += (float)v0[1] * n0; A.z += (float)v0[2] * n0; A.w += (float)v0[3] * n0;
        A.x += (float)v1[0] * n1; A.y += (float)v1[1] * n1; A.z += (float)v1[2] * n1; A.w += (float)v1[3] * n1;
        A.x += (float)v2[0] * n2; A.y += (float)v2[1] * n2; A.z += (float)v2[2] * n2; A.w += (float)v2[3] * n2;
        A.x += (float)v3[0] * n3; A.y += (float)v3[1] * n3; A.z += (float)v3[2] * n3; A.w += (float)v3[3] * n3;
    }
    for (; e < end; ++e) {
        int2 ee = edata[e];
        half4v v = h4[(size_t)ee.x * 32 + ln];
        float nr = __int_as_float(ee.y);
        A.x += (float)v[0] * nr; A.y += (float)v[1] * nr;
        A.z += (float)v[2] * nr; A.w += (float)v[3] * nr;
    }
}

// ---------------- fused layer: aggregate(hin) -> LDS split-bf16 -> MFMA GEMM ----------------
// 32 nodes/block, 16 KB LDS, 8 blocks/CU. Phase 1 (MLP-maximized): all metadata
// (rp, dis, self, edata-preload) for the group's 4 nodes hoisted up front
// (2 round trips), then pair-interleaved gathers (8 loads in flight).
// Phase 2: 4 waves = (row-group rg, col-half ch); each wave does 16 rows x 4 tc.
// LAST: emb fp32 + fused head (Wr1 MFMA + Wr2 reduce; cross-ch partials via LDS).

template <bool LAST>
__global__ __launch_bounds__(256, 8) void fused_layer_kernel(
    const _Float16* __restrict__ hin,
    const int* __restrict__ rp, const int2* __restrict__ edata,
    const float* __restrict__ dis,
    const unsigned short* __restrict__ whi, const unsigned short* __restrict__ wlo,
    const float* __restrict__ bias,
    void* __restrict__ outv,
    const unsigned short* __restrict__ w1hi, const unsigned short* __restrict__ w1lo,
    const float* __restrict__ br1, const float* __restrict__ Wr2,
    const float* __restrict__ br2, float* __restrict__ pred,
    int N) {
    __shared__ unsigned short sAh[4096];   // 32 rows x 128 cols, swizzled
    __shared__ unsigned short sAl[4096];
    int t = threadIdx.x;
    int node0 = blockIdx.x * 32;

    // ---- phase 1: aggregation into LDS ----
    {
        int g = t >> 5, ln = t & 31;
        const half4v* h4 = (const half4v*)hin;
        int nb = node0 + g * 4;

        // metadata for all 4 nodes, hoisted (independent loads)
        int r0 = rp[min(nb + 0, N)];
        int r1 = rp[min(nb + 1, N)];
        int r2 = rp[min(nb + 2, N)];
        int r3 = rp[min(nb + 3, N)];
        int r4 = rp[min(nb + 4, N)];
        float d0 = dis[min(nb + 0, N - 1)];
        float d1 = dis[min(nb + 1, N - 1)];
        float d2 = dis[min(nb + 2, N - 1)];
        float d3 = dis[min(nb + 3, N - 1)];
        half4v s0 = h4[(size_t)min(nb + 0, N - 1) * 32 + ln];
        half4v s1 = h4[(size_t)min(nb + 1, N - 1) * 32 + ln];
        half4v s2 = h4[(size_t)min(nb + 2, N - 1) * 32 + ln];
        half4v s3 = h4[(size_t)min(nb + 3, N - 1) * 32 + ln];
        int deg0 = (nb + 0 < N) ? r1 - r0 : 0;
        int deg1 = (nb + 1 < N) ? r2 - r1 : 0;
        int deg2 = (nb + 2 < N) ? r3 - r2 : 0;
        int deg3 = (nb + 3 < N) ? r4 - r3 : 0;
        int2 m0 = make_int2(0, 0), m1 = make_int2(0, 0);
        int2 m2 = make_int2(0, 0), m3 = make_int2(0, 0);
        if (deg0 > 0) m0 = edata[r0 + min(ln, deg0 - 1)];
        if (deg1 > 0) m1 = edata[r1 + min(ln, deg1 - 1)];
        if (deg2 > 0) m2 = edata[r2 + min(ln, deg2 - 1)];
        if (deg3 > 0) m3 = edata[r3 + min(ln, deg3 - 1)];

        float sc0 = (nb + 0 < N) ? d0 * d0 : 0.f;
        float sc1 = (nb + 1 < N) ? d1 * d1 : 0.f;
        float sc2 = (nb + 2 < N) ? d2 * d2 : 0.f;
        float sc3 = (nb + 3 < N) ? d3 * d3 : 0.f;
        float4 A0 = make_float4((float)s0[0] * sc0, (float)s0[1] * sc0,
                                (float)s0[2] * sc0, (float)s0[3] * sc0);
        float4 A1 = make_float4((float)s1[0] * sc1, (float)s1[1] * sc1,
                                (float)s1[2] * sc1, (float)s1[3] * sc1);
        float4 A2 = make_float4((float)s2[0] * sc2, (float)s2[1] * sc2,
                                (float)s2[2] * sc2, (float)s2[3] * sc2);
        float4 A3 = make_float4((float)s3[0] * sc3, (float)s3[1] * sc3,
                                (float)s3[2] * sc3, (float)s3[3] * sc3);

        gpair(h4, ln, m0, min(deg0, 32), A0, m1, min(deg1, 32), A1);
        gpair(h4, ln, m2, min(deg2, 32), A2, m3, min(deg3, 32), A3);
        // rare deg>32 tails (order-preserving)
        if (deg0 > 32) gtail(h4, ln, edata, r0 + 32, r0 + deg0, A0);
        if (deg1 > 32) gtail(h4, ln, edata, r1 + 32, r1 + deg1, A1);
        if (deg2 > 32) gtail(h4, ln, edata, r2 + 32, r2 + deg2, A2);
        if (deg3 > 32) gtail(h4, ln, edata, r3 + 32, r3 + deg3, A3);

        auto store_row = [&](int r, const float4& A) {
            ushort4 hh, ll;
            split2(A.x, hh.x, ll.x);
            split2(A.y, hh.y, ll.y);
            split2(A.z, hh.z, ll.z);
            split2(A.w, hh.w, ll.w);
            int bo = (r * 256 + ln * 8) ^ ((r & 7) << 4);
            *(ushort4*)((char*)sAh + bo) = hh;
            *(ushort4*)((char*)sAl + bo) = ll;
        };
        store_row(g * 4 + 0, A0);
        store_row(g * 4 + 1, A1);
        store_row(g * 4 + 2, A2);
        store_row(g * 4 + 3, A3);
    }
    __syncthreads();

    // ---- phase 2: MFMA GEMM from LDS ----
    int wv = t >> 6, ln2 = t & 63;
    int m = ln2 & 15, q = ln2 >> 4;
    int rg = wv & 1, ch = wv >> 1;
    int rloc = rg * 16 + m;
    int tcb = ch * 4;

    f32x4 acc[4];
    #pragma unroll
    for (int i = 0; i < 4; ++i) acc[i] = (f32x4)(0.f);

    #pragma unroll
    for (int chunk = 0; chunk < 4; ++chunk) {
        int bo = (rloc * 256 + q * 16 + chunk * 64) ^ ((rloc & 7) << 4);
        short8 af = *(const short8*)((const char*)sAh + bo);
        short8 lf = *(const short8*)((const char*)sAl + bo);
        const unsigned short* wb = whi + (size_t)(chunk * 8 + tcb) * 512 + ln2 * 8;
        const unsigned short* wc = wlo + (size_t)(chunk * 8 + tcb) * 512 + ln2 * 8;
        #pragma unroll
        for (int j = 0; j < 4; ++j) {
            short8 wh = *(const short8*)(wb + j * 512);
            short8 wl = *(const short8*)(wc + j * 512);
            acc[j] = __builtin_amdgcn_mfma_f32_16x16x32_bf16(af, wh, acc[j], 0, 0, 0);
            acc[j] = __builtin_amdgcn_mfma_f32_16x16x32_bf16(lf, wh, acc[j], 0, 0, 0);
            acc[j] = __builtin_amdgcn_mfma_f32_16x16x32_bf16(af, wl, acc[j], 0, 0, 0);
        }
    }

    // C/D layout: col = lane&15, row = (lane>>4)*4 + reg  [m89/m91-verified]
    int crow = node0 + rg * 16 + q * 4;

    if constexpr (!LAST) {
        _Float16* hout = (_Float16*)outv;
        #pragma unroll
        for (int j = 0; j < 4; ++j) {
            int col = (tcb + j) * 16 + m;
            float b = bias[col];
            #pragma unroll
            for (int r = 0; r < 4; ++r) {
                int rr = crow + r;
                if (rr < N) {
                    float v = fmaxf(acc[j][r] + b, 0.f);
                    hout[(size_t)rr * 128 + col] = (_Float16)v;
                }
            }
        }
    } else {
        __shared__ float pbuf[2][16][3];
        // emb write: fp32 nontemporal, no relu
        float* emb = (float*)outv;
        #pragma unroll
        for (int j = 0; j < 4; ++j) {
            int col = (tcb + j) * 16 + m;
            float b = bias[col];
            #pragma unroll
            for (int r = 0; r < 4; ++r) {
                int rr = crow + r;
                if (rr < N)
                    __builtin_nontemporal_store(acc[j][r] + b, &emb[(size_t)rr * 128 + col]);
            }
        }
        __syncthreads();  // all phase-2 LDS reads complete before overwrite
        // relu + split acc back into LDS (C-layout -> A-layout redistribution)
        #pragma unroll
        for (int j = 0; j < 4; ++j) {
            int col = (tcb + j) * 16 + m;
            float b = bias[col];
            #pragma unroll
            for (int r = 0; r < 4; ++r) {
                int r2 = rg * 16 + q * 4 + r;
                float v = fmaxf(acc[j][r] + b, 0.f);
                unsigned short hi, lo;
                split2(v, hi, lo);
                int bo = (r2 * 256 + col * 2) ^ ((r2 & 7) << 4);
                *(unsigned short*)((char*)sAh + bo) = hi;
                *(unsigned short*)((char*)sAl + bo) = lo;
            }
        }
        __syncthreads();
        // head MFMA: relu(emb) @ Wr1 (this wave's 4 tc columns)
        f32x4 acc2[4];
        #pragma unroll
        for (int i = 0; i < 4; ++i) acc2[i] = (f32x4)(0.f);
        #pragma unroll
        for (int chunk = 0; chunk < 4; ++chunk) {
            int bo = (rloc * 256 + q * 16 + chunk * 64) ^ ((rloc & 7) << 4);
            short8 af = *(const short8*)((const char*)sAh + bo);
            short8 lf = *(const short8*)((const char*)sAl + bo);
            const unsigned short* wb = w1hi + (size_t)(chunk * 8 + tcb) * 512 + ln2 * 8;
            const unsigned short* wc = w1lo + (size_t)(chunk * 8 + tcb) * 512 + ln2 * 8;
            #pragma unroll
            for (int j = 0; j < 4; ++j) {
                short8 wh = *(const short8*)(wb + j * 512);
                short8 wl = *(const short8*)(wc + j * 512);
                acc2[j] = __builtin_amdgcn_mfma_f32_16x16x32_bf16(af, wh, acc2[j], 0, 0, 0);
                acc2[j] = __builtin_amdgcn_mfma_f32_16x16x32_bf16(lf, wh, acc2[j], 0, 0, 0);
                acc2[j] = __builtin_amdgcn_mfma_f32_16x16x32_bf16(af, wl, acc2[j], 0, 0, 0);
            }
        }
        // relu(h @ Wr1 + br1) @ Wr2 + br2: partial over this wave's 64 cols
        float p0[4] = {0.f, 0.f, 0.f, 0.f};
        float p1[4] = {0.f, 0.f, 0.f, 0.f};
        float p2[4] = {0.f, 0.f, 0.f, 0.f};
        #pragma unroll
        for (int j = 0; j < 4; ++j) {
            int col = (tcb + j) * 16 + m;
            float b1 = br1[col];
            float w0 = Wr2[col * 3 + 0], w1 = Wr2[col * 3 + 1], w2 = Wr2[col * 3 + 2];
            #pragma unroll
            for (int r = 0; r < 4; ++r) {
                float hv = fmaxf(acc2[j][r] + b1, 0.f);
                p0[r] += hv * w0;
                p1[r] += hv * w1;
                p2[r] += hv * w2;
            }
        }
        #pragma unroll
        for (int mask = 1; mask < 16; mask <<= 1) {
            #pragma unroll
            for (int r = 0; r < 4; ++r) {
                p0[r] += __shfl_xor(p0[r], mask);
                p1[r] += __shfl_xor(p1[r], mask);
                p2[r] += __shfl_xor(p2[r], mask);
            }
        }
        if (ch == 1 && m == 0) {
            #pragma unroll
            for (int r = 0; r < 4; ++r) {
                pbuf[rg][q * 4 + r][0] = p0[r];
                pbuf[rg][q * 4 + r][1] = p1[r];
                pbuf[rg][q * 4 + r][2] = p2[r];
            }
        }
        __syncthreads();
        if (ch == 0 && m == 0) {
            #pragma unroll
            for (int r = 0; r < 4; ++r) {
                int rr = crow + r;
                if (rr < N) {
                    float o0 = p0[r] + pbuf[rg][q * 4 + r][0] + br2[0];
                    float o1 = p1[r] + pbuf[rg][q * 4 + r][1] + br2[1];
                    float o2 = p2[r] + pbuf[rg][q * 4 + r][2] + br2[2];
                    __builtin_nontemporal_store(o0, &pred[(size_t)rr * 3 + 0]);
                    __builtin_nontemporal_store(o1, &pred[(size_t)rr * 3 + 1]);
                    __builtin_nontemporal_store(o2, &pred[(size_t)rr * 3 + 2]);
                }
            }
        }
    }
}

// ---------------- launch ----------------

extern "C" void kernel_launch(void* const* d_in, const int* in_sizes, int n_in,
                              void* d_out, int out_size, void* d_ws, size_t ws_size,
                              hipStream_t stream) {
    const float* x   = (const float*)d_in[0];
    const float* xm  = (const float*)d_in[1];
    const int*   ei  = (const int*)d_in[2];
    const float* W0  = (const float*)d_in[3];
    const float* b0  = (const float*)d_in[4];
    const float* Wh  = (const float*)d_in[5];
    const float* bh  = (const float*)d_in[6];
    const float* Wr1 = (const float*)d_in[7];
    const float* br1 = (const float*)d_in[8];
    const float* Wr2 = (const float*)d_in[9];
    const float* br2 = (const float*)d_in[10];
    float* out = (float*)d_out;

    int N = in_sizes[0] / 10;
    int E = in_sizes[2] / 2;
    const int* src = ei;
    const int* dst = ei + E;

    float* emb_out  = out;                   // N x 128 (final GCN layer writes here)
    float* pred_out = out + (size_t)N * 128; // N x 3

    char* ws = (char*)d_ws;
    size_t off = 0;
    auto alloc = [&](size_t bytes) -> void* {
        void* p = ws + off;
        off += (bytes + 255) & ~(size_t)255;
        return p;
    };
    // h ping-pong buffers (fp16, 25.6 MB each). h0/agg16out alias bufB's head
    // (both dead before bufB's first write at layer l=0's output).
    _Float16* bufA = (_Float16*)alloc((size_t)N * 128 * 2);
    _Float16* bufB = (_Float16*)alloc((size_t)N * 128 * 2);
    float* h0       = (float*)bufB;
    float* agg16out = h0 + (size_t)N * 16;
    int*   cnt      = (int*)alloc((size_t)N * 4);
    float* dis      = (float*)alloc((size_t)N * 4);
    int*   rp       = (int*)alloc((size_t)(N + 1) * 4);
    int*   cursor   = (int*)alloc((size_t)N * 4);
    int2*  edata    = (int2*)alloc((size_t)E * 8);
    int*   partials = (int*)alloc((size_t)1024 * 4);
    unsigned short* whi = (unsigned short*)alloc((size_t)5 * 16384 * 2);
    unsigned short* wlo = (unsigned short*)alloc((size_t)5 * 16384 * 2);
    (void)ws_size;  // ~59.3 MB total, well under the previously-proven budget

    int gN = (N + 255) / 256, gE = (E + 255) / 256;
    int gRows = (N + 63) / 64;
    int gRows32 = (N + 31) / 32;
    int nScanBlocks = (N + 1023) / 1024;

    zero_ints<<<gN, 256, 0, stream>>>(cnt, N);
    count_deg<<<gE, 256, 0, stream>>>(dst, cnt, E);
    compute_dis<<<gN, 256, 0, stream>>>(cnt, dis, N);
    scan_block_sums<<<nScanBlocks, 256, 0, stream>>>(cnt, partials, N);
    scan_partials<<<1, 256, 0, stream>>>(partials, nScanBlocks, rp, N);
    scan_write<<<nScanBlocks, 256, 0, stream>>>(cnt, partials, rp, cursor, N);
    scatter_edges<<<gE, 256, 0, stream>>>(src, dst, dis, cursor, edata, E);
    build_h0<<<(N * 16 + 255) / 256, 256, 0, stream>>>(x, xm, h0, N);
    wsplit_kernel<<<5 * 16384 / 256, 256, 0, stream>>>(Wh, Wr1, whi, wlo);

    // layer 0 (in_dim=16): aggregate in 16-dim, then VALU GEMM -> relu -> fp16 bufA
    agg16_kernel<<<(N + 15) / 16, 256, 0, stream>>>(h0, rp, edata, dis, agg16out, N);
    gemm_kernel<16, 1><<<gRows, 256, 0, stream>>>(agg16out, W0, b0, bufA, N);

    // hidden layers 1..3: fused aggregate + MFMA GEMM, ping-ponging bufA/bufB
    fused_layer_kernel<false><<<gRows32, 256, 0, stream>>>(
        bufA, rp, edata, dis, whi, wlo, bh, bufB,
        nullptr, nullptr, nullptr, nullptr, nullptr, nullptr, N);
    fused_layer_kernel<false><<<gRows32, 256, 0, stream>>>(
        bufB, rp, edata, dis, whi + 16384, wlo + 16384, bh + 128, bufA,
        nullptr, nullptr, nullptr, nullptr, nullptr, nullptr, N);
    fused_layer_kernel<false><<<gRows32, 256, 0, stream>>>(
        bufA, rp, edata, dis, whi + 2 * 16384, wlo + 2 * 16384, bh + 2 * 128, bufB,
        nullptr, nullptr, nullptr, nullptr, nullptr, nullptr, N);
    // final layer: fused aggregate + GEMM -> emb (fp32) + fused head -> pred
    fused_layer_kernel<true><<<gRows32, 256, 0, stream>>>(
        bufB, rp, edata, dis, whi + 3 * 16384, wlo + 3 * 16384, bh + 3 * 128, emb_out,
        whi + 4 * 16384, wlo + 4 * 16384, br1, Wr2, br2, pred_out, N);
}

// Round 5
// 494.277 us; speedup vs baseline: 1.1330x; 1.1330x over previous
//
#include <hip/hip_runtime.h>
#include <cstdint>
#include <cstddef>

typedef __attribute__((ext_vector_type(8))) short short8;
typedef __attribute__((ext_vector_type(4))) float f32x4;
typedef __attribute__((ext_vector_type(4))) _Float16 half4v;
typedef __attribute__((ext_vector_type(2))) _Float16 half2v;

// ---------------- bf16 split helpers (round-to-nearest-even) ----------------

__device__ inline unsigned short f2bf(float f) {
    unsigned int u = __float_as_uint(f);
    u = u + 0x7fff + ((u >> 16) & 1);
    return (unsigned short)(u >> 16);
}
__device__ inline float bf2f(unsigned short h) {
    return __uint_as_float(((unsigned int)h) << 16);
}
__device__ inline void split2(float v, unsigned short& hi, unsigned short& lo) {
    hi = f2bf(v);
    lo = f2bf(v - bf2f(hi));
}

// ---------------- preprocessing kernels ----------------

__global__ void zero_ints(int* p, int n) {
    int i = blockIdx.x * 256 + threadIdx.x;
    if (i < n) p[i] = 0;
}

__global__ void count_deg(const int* __restrict__ dst, int* __restrict__ cnt, int E) {
    int i = blockIdx.x * 256 + threadIdx.x;
    if (i < E) atomicAdd(&cnt[dst[i]], 1);
}

__global__ void compute_dis(const int* __restrict__ cnt, float* __restrict__ dis, int N) {
    int i = blockIdx.x * 256 + threadIdx.x;
    if (i < N) dis[i] = rsqrtf((float)cnt[i] + 1.0f);
}

// ---------------- 3-phase parallel exclusive scan over cnt -> rp, cursor ----------------

__global__ __launch_bounds__(256) void scan_block_sums(const int* __restrict__ cnt,
                                                       int* __restrict__ partials, int N) {
    __shared__ int s[256];
    int t = threadIdx.x;
    int base = blockIdx.x * 1024 + t * 4;
    int v = 0;
    if (base + 3 < N) {
        int4 d = *(const int4*)&cnt[base];
        v = d.x + d.y + d.z + d.w;
    } else {
        for (int j = 0; j < 4; ++j) if (base + j < N) v += cnt[base + j];
    }
    s[t] = v;
    __syncthreads();
    for (int off = 128; off > 0; off >>= 1) {
        if (t < off) s[t] += s[t + off];
        __syncthreads();
    }
    if (t == 0) partials[blockIdx.x] = s[0];
}

__global__ __launch_bounds__(256) void scan_partials(int* __restrict__ partials, int nb,
                                                     int* __restrict__ rp, int N) {
    __shared__ int s[256];
    int t = threadIdx.x;
    int base = t * 4;
    int v0 = 0, v1 = 0, v2 = 0, v3 = 0;
    if (base < nb)     v0 = partials[base];
    if (base + 1 < nb) v1 = partials[base + 1];
    if (base + 2 < nb) v2 = partials[base + 2];
    if (base + 3 < nb) v3 = partials[base + 3];
    s[t] = v0 + v1 + v2 + v3;
    __syncthreads();
    for (int off = 1; off < 256; off <<= 1) {
        int v = s[t];
        int u = (t >= off) ? s[t - off] : 0;
        __syncthreads();
        s[t] = v + u;
        __syncthreads();
    }
    int run = (t == 0) ? 0 : s[t - 1];
    if (base < nb)     { partials[base] = run;     run += v0; }
    if (base + 1 < nb) { partials[base + 1] = run; run += v1; }
    if (base + 2 < nb) { partials[base + 2] = run; run += v2; }
    if (base + 3 < nb) { partials[base + 3] = run; run += v3; }
    if (t == 255) rp[N] = s[255];
}

__global__ __launch_bounds__(256) void scan_write(const int* __restrict__ cnt,
                                                  const int* __restrict__ partials,
                                                  int* __restrict__ rp,
                                                  int* __restrict__ cursor, int N) {
    __shared__ int s[256];
    int t = threadIdx.x;
    int base = blockIdx.x * 1024 + t * 4;
    int v0 = 0, v1 = 0, v2 = 0, v3 = 0;
    if (base + 3 < N) {
        int4 d = *(const int4*)&cnt[base];
        v0 = d.x; v1 = d.y; v2 = d.z; v3 = d.w;
    } else {
        if (base < N)     v0 = cnt[base];
        if (base + 1 < N) v1 = cnt[base + 1];
        if (base + 2 < N) v2 = cnt[base + 2];
    }
    s[t] = v0 + v1 + v2 + v3;
    __syncthreads();
    for (int off = 1; off < 256; off <<= 1) {
        int v = s[t];
        int u = (t >= off) ? s[t - off] : 0;
        __syncthreads();
        s[t] = v + u;
        __syncthreads();
    }
    int run = partials[blockIdx.x] + ((t == 0) ? 0 : s[t - 1]);
    int4 o;
    o.x = run; run += v0;
    o.y = run; run += v1;
    o.z = run; run += v2;
    o.w = run; run += v3;
    if (base + 3 < N) {
        *(int4*)&rp[base] = o;
        *(int4*)&cursor[base] = o;
    } else {
        if (base < N)     { rp[base] = o.x;     cursor[base] = o.x; }
        if (base + 1 < N) { rp[base + 1] = o.y; cursor[base + 1] = o.y; }
        if (base + 2 < N) { rp[base + 2] = o.z; cursor[base + 2] = o.z; }
    }
}

// edata[pos] = (src, bitcast(norm)) — one 8B record per edge
__global__ void scatter_edges(const int* __restrict__ src, const int* __restrict__ dstv,
                              const float* __restrict__ dis, int* __restrict__ cursor,
                              int2* __restrict__ edata, int E) {
    int i = blockIdx.x * 256 + threadIdx.x;
    if (i < E) {
        int s = src[i], d = dstv[i];
        int pos = atomicAdd(&cursor[d], 1);
        edata[pos] = make_int2(s, __float_as_int(dis[s] * dis[d]));
    }
}

__global__ void build_h0(const float* __restrict__ x, const float* __restrict__ xm,
                         float* __restrict__ h0, int N) {
    int i = blockIdx.x * 256 + threadIdx.x;
    if (i < N * 16) {
        int node = i >> 4, f = i & 15;
        h0[i] = (f < 8) ? x[node * 10 + f] : xm[node * 10 + f - 8];
    }
}

// ---------------- W split into MFMA B-fragment order ----------------

__global__ __launch_bounds__(256) void wsplit_kernel(const float* __restrict__ Wh,
                                                     const float* __restrict__ Wr1,
                                                     unsigned short* __restrict__ whi,
                                                     unsigned short* __restrict__ wlo) {
    int g = blockIdx.x * 256 + threadIdx.x;   // 5*16384 entries
    int l = g >> 14;
    int idx = g & 16383;
    int j = idx & 7;
    int lane = (idx >> 3) & 63;
    int tcchunk = idx >> 9;                   // 0..31
    int tc = tcchunk & 7, chunk = tcchunk >> 3;
    int k = chunk * 32 + (lane >> 4) * 8 + j;
    int n = tc * 16 + (lane & 15);
    float v = (l < 4) ? Wh[l * 16384 + k * 128 + n] : Wr1[k * 128 + n];
    unsigned short hi, lo;
    split2(v, hi, lo);
    whi[g] = hi;
    wlo[g] = lo;
}

// ---------------- aggregation, 16-wide (layer 0): fp32 out ----------------
// edata preloaded by 16 lanes (covers deg<=16), batch-8 gathers.
// FP add order identical to the direct version (self, then edges ascending).

__global__ __launch_bounds__(256) void agg16_kernel(const float* __restrict__ h,
                                                    const int* __restrict__ rp,
                                                    const int2* __restrict__ edata,
                                                    const float* __restrict__ dis,
                                                    float* __restrict__ out, int N) {
    int node = blockIdx.x * 16 + (threadIdx.x >> 4);
    int tl = threadIdx.x & 15;
    if (node >= N) return;
    int beg = rp[node], end = rp[node + 1];
    int deg = end - beg;
    float di = dis[node];
    float acc = h[(size_t)node * 16 + tl] * (di * di);
    int2 my = make_int2(0, 0);
    if (deg > 0) my = edata[beg + min(tl, deg - 1)];
    int pre = min(deg, 16);
    int i = 0;
    while (i < pre) {
        int c = min(8, pre - i);
        float v[8];
        #pragma unroll
        for (int j = 0; j < 8; ++j) {
            if (j < c) {
                int sx = __shfl(my.x, i + j, 16);
                v[j] = h[(size_t)sx * 16 + tl];
            }
        }
        #pragma unroll
        for (int j = 0; j < 8; ++j) {
            if (j < c) {
                float nr = __int_as_float(__shfl(my.y, i + j, 16));
                acc += v[j] * nr;
            }
        }
        i += c;
    }
    for (int e = beg + 16; e < end; ++e) {
        int2 ee = edata[e];
        acc += h[(size_t)ee.x * 16 + tl] * __int_as_float(ee.y);
    }
    out[(size_t)node * 16 + tl] = acc;
}

// ---------------- layer-0 GEMM (K=16): VALU fp32, W in LDS; fp16 out + relu ----------------

template <int K, int OMODE>
__global__ __launch_bounds__(256, 4) void gemm_kernel(const float* __restrict__ A,
                                                      const float* __restrict__ W,
                                                      const float* __restrict__ bias,
                                                      void* __restrict__ outv, int N) {
    constexpr int KS = (K < 64) ? K : 64;
    __shared__ float sW[KS * 128];
    int t = threadIdx.x;
    int row0 = blockIdx.x * 64;
    int cg = t & 31, rg = t >> 5;
    int c0 = cg * 4;
    int r0 = row0 + rg * 8;

    const float* Ar[8];
    #pragma unroll
    for (int i = 0; i < 8; ++i) {
        int rr = min(r0 + i, N - 1);
        Ar[i] = A + (size_t)rr * K;
    }

    float4 acc[8];
    #pragma unroll
    for (int i = 0; i < 8; ++i) acc[i] = make_float4(0.f, 0.f, 0.f, 0.f);

    for (int ks = 0; ks < K; ks += KS) {
        if (ks) __syncthreads();
        for (int i = t * 4; i < KS * 128; i += 1024) {
            *(float4*)&sW[i] = *(const float4*)&W[ks * 128 + i];
        }
        __syncthreads();

        for (int kk = 0; kk < KS; kk += 4) {
            float4 a[8];
            #pragma unroll
            for (int i = 0; i < 8; ++i) a[i] = *(const float4*)&Ar[i][ks + kk];
            float4 w[4];
            #pragma unroll
            for (int j = 0; j < 4; ++j) w[j] = *(const float4*)&sW[(kk + j) * 128 + c0];
            #pragma unroll
            for (int i = 0; i < 8; ++i) {
                const float* ap = (const float*)&a[i];
                #pragma unroll
                for (int j = 0; j < 4; ++j) {
                    float av = ap[j];
                    acc[i].x += av * w[j].x;
                    acc[i].y += av * w[j].y;
                    acc[i].z += av * w[j].z;
                    acc[i].w += av * w[j].w;
                }
            }
        }
    }

    float4 bb = *(const float4*)&bias[c0];
    #pragma unroll
    for (int i = 0; i < 8; ++i) {
        int row = r0 + i;
        if (row < N) {
            float4 v;
            v.x = fmaxf(acc[i].x + bb.x, 0.f); v.y = fmaxf(acc[i].y + bb.y, 0.f);
            v.z = fmaxf(acc[i].z + bb.z, 0.f); v.w = fmaxf(acc[i].w + bb.w, 0.f);
            if (OMODE == 1) {
                half4v o;
                o[0] = (_Float16)v.x; o[1] = (_Float16)v.y;
                o[2] = (_Float16)v.z; o[3] = (_Float16)v.w;
                *(half4v*)&((_Float16*)outv)[(size_t)row * 128 + c0] = o;
            } else {
                *(float4*)&((float*)outv)[(size_t)row * 128 + c0] = v;
            }
        }
    }
}

// ---------------- fused layer: aggregate(hin) -> LDS split-bf16 -> MFMA GEMM ----------------
// 32 nodes/block, 16 KB LDS, 8 blocks/CU.
// Phase 1 (wave-scalar edges): ONE WAVE per node (lane ln owns features 2ln,2ln+1).
// Node metadata + a 16-record edge burst are wave-uniform -> scalar loads (SMEM),
// no ds_bpermute, SALU edge addresses. 16 gathers in flight; j>=deg gathers are
// clamped to rec[0] with norm 0 (exact no-op). deg>16 tail (P~0.4%) is serial.
// FP add order per node: self, then edges ascending (bit-identical to prior rounds).
// NOTE: the unconditional 16-record burst may read <=120B past edata's end; that
// region is the mapped partials/whi workspace — loaded but never used as address.
// Phase 2: 4 waves = (row-group rg, col-half ch); each wave does 16 rows x 4 tc.
// LAST: emb fp32 + fused head (Wr1 MFMA + Wr2 reduce; cross-ch partials via LDS).

template <bool LAST>
__global__ __launch_bounds__(256, 8) void fused_layer_kernel(
    const _Float16* __restrict__ hin,
    const int* __restrict__ rp, const int2* __restrict__ edata,
    const float* __restrict__ dis,
    const unsigned short* __restrict__ whi, const unsigned short* __restrict__ wlo,
    const float* __restrict__ bias,
    void* __restrict__ outv,
    const unsigned short* __restrict__ w1hi, const unsigned short* __restrict__ w1lo,
    const float* __restrict__ br1, const float* __restrict__ Wr2,
    const float* __restrict__ br2, float* __restrict__ pred,
    int N) {
    __shared__ unsigned short sAh[4096];   // 32 rows x 128 cols, swizzled
    __shared__ unsigned short sAl[4096];
    int t = threadIdx.x;
    int node0 = blockIdx.x * 32;

    // ---- phase 1: aggregation into LDS (one wave per node) ----
    {
        int wv1 = __builtin_amdgcn_readfirstlane(t >> 6);
        int ln = t & 63;
        const half2v* hb = (const half2v*)hin;

        #pragma unroll 1
        for (int it = 0; it < 8; ++it) {
            int r = wv1 * 8 + it;
            int node = node0 + r;
            float a0 = 0.f, a1 = 0.f;
            if (node < N) {
                int beg = rp[node];
                int end = rp[node + 1];
                int deg = end - beg;
                float di = dis[node];
                float sc = di * di;
                half2v sv = hb[(size_t)node * 64 + ln];
                a0 = (float)sv[0] * sc;
                a1 = (float)sv[1] * sc;
                if (deg > 0) {
                    const int2* ep = edata + beg;
                    int2 rec[16];
                    #pragma unroll
                    for (int j = 0; j < 16; ++j) rec[j] = ep[j];
                    int c = min(deg, 16);
                    int ix0 = rec[0].x;
                    half2v va[16];
                    #pragma unroll
                    for (int j = 0; j < 16; ++j) {
                        int ix = (j < c) ? rec[j].x : ix0;
                        va[j] = hb[(size_t)ix * 64 + ln];
                    }
                    #pragma unroll
                    for (int j = 0; j < 16; ++j) {
                        float nr = (j < c) ? __int_as_float(rec[j].y) : 0.f;
                        a0 += nr * (float)va[j][0];
                        a1 += nr * (float)va[j][1];
                    }
                    for (int e = 16; e < deg; ++e) {
                        int2 rr2 = ep[e];
                        half2v v = hb[(size_t)rr2.x * 64 + ln];
                        float nr = __int_as_float(rr2.y);
                        a0 += nr * (float)v[0];
                        a1 += nr * (float)v[1];
                    }
                }
            }
            unsigned short h0_, l0_, h1_, l1_;
            split2(a0, h0_, l0_);
            split2(a1, h1_, l1_);
            int bo = (r * 256 + ln * 4) ^ ((r & 7) << 4);
            ushort2 hh; hh.x = h0_; hh.y = h1_;
            ushort2 ll; ll.x = l0_; ll.y = l1_;
            *(ushort2*)((char*)sAh + bo) = hh;
            *(ushort2*)((char*)sAl + bo) = ll;
        }
    }
    __syncthreads();

    // ---- phase 2: MFMA GEMM from LDS ----
    int wv = t >> 6, ln2 = t & 63;
    int m = ln2 & 15, q = ln2 >> 4;
    int rg = wv & 1, ch = wv >> 1;
    int rloc = rg * 16 + m;
    int tcb = ch * 4;

    f32x4 acc[4];
    #pragma unroll
    for (int i = 0; i < 4; ++i) acc[i] = (f32x4)(0.f);

    #pragma unroll
    for (int chunk = 0; chunk < 4; ++chunk) {
        int bo = (rloc * 256 + q * 16 + chunk * 64) ^ ((rloc & 7) << 4);
        short8 af = *(const short8*)((const char*)sAh + bo);
        short8 lf = *(const short8*)((const char*)sAl + bo);
        const unsigned short* wb = whi + (size_t)(chunk * 8 + tcb) * 512 + ln2 * 8;
        const unsigned short* wc = wlo + (size_t)(chunk * 8 + tcb) * 512 + ln2 * 8;
        #pragma unroll
        for (int j = 0; j < 4; ++j) {
            short8 wh = *(const short8*)(wb + j * 512);
            short8 wl = *(const short8*)(wc + j * 512);
            acc[j] = __builtin_amdgcn_mfma_f32_16x16x32_bf16(af, wh, acc[j], 0, 0, 0);
            acc[j] = __builtin_amdgcn_mfma_f32_16x16x32_bf16(lf, wh, acc[j], 0, 0, 0);
            acc[j] = __builtin_amdgcn_mfma_f32_16x16x32_bf16(af, wl, acc[j], 0, 0, 0);
        }
    }

    // C/D layout: col = lane&15, row = (lane>>4)*4 + reg  [m89/m91-verified]
    int crow = node0 + rg * 16 + q * 4;

    if constexpr (!LAST) {
        _Float16* hout = (_Float16*)outv;
        #pragma unroll
        for (int j = 0; j < 4; ++j) {
            int col = (tcb + j) * 16 + m;
            float b = bias[col];
            #pragma unroll
            for (int r = 0; r < 4; ++r) {
                int rr = crow + r;
                if (rr < N) {
                    float v = fmaxf(acc[j][r] + b, 0.f);
                    hout[(size_t)rr * 128 + col] = (_Float16)v;
                }
            }
        }
    } else {
        __shared__ float pbuf[2][16][3];
        // emb write: fp32 nontemporal, no relu
        float* emb = (float*)outv;
        #pragma unroll
        for (int j = 0; j < 4; ++j) {
            int col = (tcb + j) * 16 + m;
            float b = bias[col];
            #pragma unroll
            for (int r = 0; r < 4; ++r) {
                int rr = crow + r;
                if (rr < N)
                    __builtin_nontemporal_store(acc[j][r] + b, &emb[(size_t)rr * 128 + col]);
            }
        }
        __syncthreads();  // all phase-2 LDS reads complete before overwrite
        // relu + split acc back into LDS (C-layout -> A-layout redistribution)
        #pragma unroll
        for (int j = 0; j < 4; ++j) {
            int col = (tcb + j) * 16 + m;
            float b = bias[col];
            #pragma unroll
            for (int r = 0; r < 4; ++r) {
                int r2 = rg * 16 + q * 4 + r;
                float v = fmaxf(acc[j][r] + b, 0.f);
                unsigned short hi, lo;
                split2(v, hi, lo);
                int bo = (r2 * 256 + col * 2) ^ ((r2 & 7) << 4);
                *(unsigned short*)((char*)sAh + bo) = hi;
                *(unsigned short*)((char*)sAl + bo) = lo;
            }
        }
        __syncthreads();
        // head MFMA: relu(emb) @ Wr1 (this wave's 4 tc columns)
        f32x4 acc2[4];
        #pragma unroll
        for (int i = 0; i < 4; ++i) acc2[i] = (f32x4)(0.f);
        #pragma unroll
        for (int chunk = 0; chunk < 4; ++chunk) {
            int bo = (rloc * 256 + q * 16 + chunk * 64) ^ ((rloc & 7) << 4);
            short8 af = *(const short8*)((const char*)sAh + bo);
            short8 lf = *(const short8*)((const char*)sAl + bo);
            const unsigned short* wb = w1hi + (size_t)(chunk * 8 + tcb) * 512 + ln2 * 8;
            const unsigned short* wc = w1lo + (size_t)(chunk * 8 + tcb) * 512 + ln2 * 8;
            #pragma unroll
            for (int j = 0; j < 4; ++j) {
                short8 wh = *(const short8*)(wb + j * 512);
                short8 wl = *(const short8*)(wc + j * 512);
                acc2[j] = __builtin_amdgcn_mfma_f32_16x16x32_bf16(af, wh, acc2[j], 0, 0, 0);
                acc2[j] = __builtin_amdgcn_mfma_f32_16x16x32_bf16(lf, wh, acc2[j], 0, 0, 0);
                acc2[j] = __builtin_amdgcn_mfma_f32_16x16x32_bf16(af, wl, acc2[j], 0, 0, 0);
            }
        }
        // relu(h @ Wr1 + br1) @ Wr2 + br2: partial over this wave's 64 cols
        float p0[4] = {0.f, 0.f, 0.f, 0.f};
        float p1[4] = {0.f, 0.f, 0.f, 0.f};
        float p2[4] = {0.f, 0.f, 0.f, 0.f};
        #pragma unroll
        for (int j = 0; j < 4; ++j) {
            int col = (tcb + j) * 16 + m;
            float b1 = br1[col];
            float w0 = Wr2[col * 3 + 0], w1 = Wr2[col * 3 + 1], w2 = Wr2[col * 3 + 2];
            #pragma unroll
            for (int r = 0; r < 4; ++r) {
                float hv = fmaxf(acc2[j][r] + b1, 0.f);
                p0[r] += hv * w0;
                p1[r] += hv * w1;
                p2[r] += hv * w2;
            }
        }
        #pragma unroll
        for (int mask = 1; mask < 16; mask <<= 1) {
            #pragma unroll
            for (int r = 0; r < 4; ++r) {
                p0[r] += __shfl_xor(p0[r], mask);
                p1[r] += __shfl_xor(p1[r], mask);
                p2[r] += __shfl_xor(p2[r], mask);
            }
        }
        if (ch == 1 && m == 0) {
            #pragma unroll
            for (int r = 0; r < 4; ++r) {
                pbuf[rg][q * 4 + r][0] = p0[r];
                pbuf[rg][q * 4 + r][1] = p1[r];
                pbuf[rg][q * 4 + r][2] = p2[r];
            }
        }
        __syncthreads();
        if (ch == 0 && m == 0) {
            #pragma unroll
            for (int r = 0; r < 4; ++r) {
                int rr = crow + r;
                if (rr < N) {
                    float o0 = p0[r] + pbuf[rg][q * 4 + r][0] + br2[0];
                    float o1 = p1[r] + pbuf[rg][q * 4 + r][1] + br2[1];
                    float o2 = p2[r] + pbuf[rg][q * 4 + r][2] + br2[2];
                    __builtin_nontemporal_store(o0, &pred[(size_t)rr * 3 + 0]);
                    __builtin_nontemporal_store(o1, &pred[(size_t)rr * 3 + 1]);
                    __builtin_nontemporal_store(o2, &pred[(size_t)rr * 3 + 2]);
                }
            }
        }
    }
}

// ---------------- launch ----------------

extern "C" void kernel_launch(void* const* d_in, const int* in_sizes, int n_in,
                              void* d_out, int out_size, void* d_ws, size_t ws_size,
                              hipStream_t stream) {
    const float* x   = (const float*)d_in[0];
    const float* xm  = (const float*)d_in[1];
    const int*   ei  = (const int*)d_in[2];
    const float* W0  = (const float*)d_in[3];
    const float* b0  = (const float*)d_in[4];
    const float* Wh  = (const float*)d_in[5];
    const float* bh  = (const float*)d_in[6];
    const float* Wr1 = (const float*)d_in[7];
    const float* br1 = (const float*)d_in[8];
    const float* Wr2 = (const float*)d_in[9];
    const float* br2 = (const float*)d_in[10];
    float* out = (float*)d_out;

    int N = in_sizes[0] / 10;
    int E = in_sizes[2] / 2;
    const int* src = ei;
    const int* dst = ei + E;

    float* emb_out  = out;                   // N x 128 (final GCN layer writes here)
    float* pred_out = out + (size_t)N * 128; // N x 3

    char* ws = (char*)d_ws;
    size_t off = 0;
    auto alloc = [&](size_t bytes) -> void* {
        void* p = ws + off;
        off += (bytes + 255) & ~(size_t)255;
        return p;
    };
    // h ping-pong buffers (fp16, 25.6 MB each). h0/agg16out alias bufB's head
    // (both dead before bufB's first write at layer l=0's output).
    _Float16* bufA = (_Float16*)alloc((size_t)N * 128 * 2);
    _Float16* bufB = (_Float16*)alloc((size_t)N * 128 * 2);
    float* h0       = (float*)bufB;
    float* agg16out = h0 + (size_t)N * 16;
    int*   cnt      = (int*)alloc((size_t)N * 4);
    float* dis      = (float*)alloc((size_t)N * 4);
    int*   rp       = (int*)alloc((size_t)(N + 1) * 4);
    int*   cursor   = (int*)alloc((size_t)N * 4);
    int2*  edata    = (int2*)alloc((size_t)E * 8);
    int*   partials = (int*)alloc((size_t)1024 * 4);
    unsigned short* whi = (unsigned short*)alloc((size_t)5 * 16384 * 2);
    unsigned short* wlo = (unsigned short*)alloc((size_t)5 * 16384 * 2);
    (void)ws_size;  // ~59.3 MB total, well under the previously-proven budget

    int gN = (N + 255) / 256, gE = (E + 255) / 256;
    int gRows = (N + 63) / 64;
    int gRows32 = (N + 31) / 32;
    int nScanBlocks = (N + 1023) / 1024;

    zero_ints<<<gN, 256, 0, stream>>>(cnt, N);
    count_deg<<<gE, 256, 0, stream>>>(dst, cnt, E);
    compute_dis<<<gN, 256, 0, stream>>>(cnt, dis, N);
    scan_block_sums<<<nScanBlocks, 256, 0, stream>>>(cnt, partials, N);
    scan_partials<<<1, 256, 0, stream>>>(partials, nScanBlocks, rp, N);
    scan_write<<<nScanBlocks, 256, 0, stream>>>(cnt, partials, rp, cursor, N);
    scatter_edges<<<gE, 256, 0, stream>>>(src, dst, dis, cursor, edata, E);
    build_h0<<<(N * 16 + 255) / 256, 256, 0, stream>>>(x, xm, h0, N);
    wsplit_kernel<<<5 * 16384 / 256, 256, 0, stream>>>(Wh, Wr1, whi, wlo);

    // layer 0 (in_dim=16): aggregate in 16-dim, then VALU GEMM -> relu -> fp16 bufA
    agg16_kernel<<<(N + 15) / 16, 256, 0, stream>>>(h0, rp, edata, dis, agg16out, N);
    gemm_kernel<16, 1><<<gRows, 256, 0, stream>>>(agg16out, W0, b0, bufA, N);

    // hidden layers 1..3: fused aggregate + MFMA GEMM, ping-ponging bufA/bufB
    fused_layer_kernel<false><<<gRows32, 256, 0, stream>>>(
        bufA, rp, edata, dis, whi, wlo, bh, bufB,
        nullptr, nullptr, nullptr, nullptr, nullptr, nullptr, N);
    fused_layer_kernel<false><<<gRows32, 256, 0, stream>>>(
        bufB, rp, edata, dis, whi + 16384, wlo + 16384, bh + 128, bufA,
        nullptr, nullptr, nullptr, nullptr, nullptr, nullptr, N);
    fused_layer_kernel<false><<<gRows32, 256, 0, stream>>>(
        bufA, rp, edata, dis, whi + 2 * 16384, wlo + 2 * 16384, bh + 2 * 128, bufB,
        nullptr, nullptr, nullptr, nullptr, nullptr, nullptr, N);
    // final layer: fused aggregate + GEMM -> emb (fp32) + fused head -> pred
    fused_layer_kernel<true><<<gRows32, 256, 0, stream>>>(
        bufB, rp, edata, dis, whi + 3 * 16384, wlo + 3 * 16384, bh + 3 * 128, emb_out,
        whi + 4 * 16384, wlo + 4 * 16384, br1, Wr2, br2, pred_out, N);
}